// Round 12
// baseline (138.620 us; speedup 1.0000x reference)
//
#include <hip/hip_runtime.h>
#include <hip/hip_bf16.h>
#include <stdint.h>

typedef __attribute__((ext_vector_type(8))) short short8;
typedef __attribute__((ext_vector_type(4))) float f32x4;
typedef __attribute__((ext_vector_type(16))) float f32x16;

// Problem constants
#define BATCH 4
#define SEQ   2048
#define EMB   1024
#define HEADS 16
#define DHEAD 64
#define MROWS (BATCH * SEQ)   // 8192
#define NW    (EMB * EMB)     // 1048576

// exp(s/8) == exp2(s * 0.125*log2(e)); fold into Q at bf16-pack time
#define QSCALE 0.18033688011112042f

__device__ inline unsigned short f2bf(float f) {
    unsigned int u = __float_as_uint(f);
    unsigned int r = (u + 0x7fffu + ((u >> 16) & 1u)) >> 16;
    return (unsigned short)r;
}

__device__ __forceinline__ void gl_lds16(const short* g, short* l) {
    __builtin_amdgcn_global_load_lds(
        (const __attribute__((address_space(1))) void*)g,
        (__attribute__((address_space(3))) void*)l, 16, 0, 0);
}

template <int N>
__device__ __forceinline__ void waitvm() {
    asm volatile("s_waitcnt vmcnt(%0)" :: "n"(N) : "memory");
}

// ------- fused pack: x -> bf16 + f32 passthrough, and Wq|Wk|Wv -> bf16 ---
__global__ __launch_bounds__(256) void pack_all(const float* __restrict__ x,
                                                const float* __restrict__ wq,
                                                const float* __restrict__ wk,
                                                const float* __restrict__ wv,
                                                unsigned short* __restrict__ xb,
                                                unsigned short* __restrict__ wb,
                                                float* __restrict__ pass) {
    const int i = (blockIdx.x * 256 + threadIdx.x) * 8;
    const float* src;
    unsigned short* dst;
    bool isx = i < MROWS * EMB;
    if (isx) {
        src = x + i;
        dst = xb + i;
    } else {
        const int j = i - MROWS * EMB;
        src = (j < NW) ? wq + j : (j < 2 * NW) ? wk + (j - NW) : wv + (j - 2 * NW);
        dst = wb + j;
    }
    const float4* s = reinterpret_cast<const float4*>(src);
    float4 f0 = s[0];
    float4 f1 = s[1];
    union { unsigned short u[8]; short8 v; } o;
    o.u[0] = f2bf(f0.x); o.u[1] = f2bf(f0.y); o.u[2] = f2bf(f0.z); o.u[3] = f2bf(f0.w);
    o.u[4] = f2bf(f1.x); o.u[5] = f2bf(f1.y); o.u[6] = f2bf(f1.z); o.u[7] = f2bf(f1.w);
    *reinterpret_cast<short8*>(dst) = o.v;
    if (isx) {
        float4* p = reinterpret_cast<float4*>(pass + i);
        p[0] = f0;
        p[1] = f1;
    }
}

// ---------------- 8-wave 256-wide pipelined GEMM ------------------------
// C[m,n] = sum_k A[m,k] * B[n,k]  (NT, bf16 in), K = 1024, BK = 32.
// 3 LDS buffers, depth-2 prefetch via global_load_lds, one raw s_barrier +
// counted vmcnt per K-tile (T3+T4), setprio on MFMA (T5), granule swizzle
// via pre-swizzled global source (T2, rule #21).
// MODE 0: BN=256, cols span [Wq|Wk]; bf16 head-major out, Q scaled QSCALE.
// MODE 1: BN=128, f32 out scaled by dgp.
template <int MODE>
__global__ __launch_bounds__(512, 2) void gemm8(const short* __restrict__ A,
                                                const short* __restrict__ Bm,
                                                unsigned short* __restrict__ Cb,
                                                float* __restrict__ out,
                                                const float* __restrict__ dgp) {
    constexpr int K = EMB;
    constexpr int NT = K / 32;                 // 32 K-tiles
    constexpr int BN = (MODE == 0) ? 256 : 128;
    constexpr int NF = BN / 64;                // N-frags per wave: 4 or 2
    constexpr int BUFSTRIDE = 8192 + BN * 32;  // shorts per buffer
    constexpr int VW = 2 + BN / 128;           // vmem ops per wave per tile: 4 or 3

    __shared__ short Ks[3 * BUFSTRIDE];        // 96 KB (MODE0) / 72 KB (MODE1)

    const int t = threadIdx.x;
    const int lane = t & 63;
    const int w = t >> 6;            // 0..7
    const int wr = w >> 2;           // 0..1   M half
    const int wc = w & 3;            // 0..3   N quarter
    const int rl = lane & 15;
    const int pg = (lane >> 4) ^ (lane & 3);   // swizzled read granule
    const int m0 = blockIdx.x * 256;
    const int n0 = blockIdx.y * BN;

    const int sr = t >> 2;                     // 0..127
    const int sg = (t & 3) ^ (sr & 3);
    const int soff = sr * K + sg * 8;
    const short* gA0 = A + (size_t)(m0)*K + soff;
    const short* gA1 = A + (size_t)(m0 + 128) * K + soff;
    const short* gB0 = Bm + (size_t)(n0)*K + soff;
    const short* gB1 = Bm + (size_t)(n0 + 128) * K + soff;  // MODE0 only
    short* ldsw = Ks + w * 512;                // wave-uniform stage base

#define STAGE8(kk, bb)                                               \
    {                                                                \
        const int _k = (kk)*32;                                      \
        short* _l = ldsw + (bb)*BUFSTRIDE;                           \
        gl_lds16(gA0 + _k, _l);                                      \
        gl_lds16(gA1 + _k, _l + 4096);                               \
        gl_lds16(gB0 + _k, _l + 8192);                               \
        if (MODE == 0) gl_lds16(gB1 + _k, _l + 12288);               \
    }

    f32x4 acc[8][NF] = {};

    // prologue: tiles 0,1 -> bufs 0,1
    STAGE8(0, 0);
    STAGE8(1, 1);
    waitvm<VW>();                    // tile 0 landed
    __builtin_amdgcn_s_barrier();

    int cur = 0;
    for (int kt = 0; kt < NT; ++kt) {
        const int pf = kt + 2;
        if (pf < NT) {
            int nb = cur + 2; if (nb >= 3) nb -= 3;
            STAGE8(pf, nb);
        }

        const short* bufp = Ks + cur * BUFSTRIDE;
        short8 av[8], bv[NF];
#pragma unroll
        for (int i = 0; i < 8; i++)
            av[i] = *(const short8*)&bufp[wr * 4096 + i * 512 + rl * 32 + pg * 8];
#pragma unroll
        for (int j = 0; j < NF; j++) {
            const int brow = (MODE == 0) ? ((wc & 1) * 64 + j * 16 + rl)
                                         : (wc * 32 + j * 16 + rl);
            const int bh = (MODE == 0) ? (wc >> 1) : 0;
            bv[j] = *(const short8*)&bufp[8192 + bh * 4096 + brow * 32 + pg * 8];
        }

        __builtin_amdgcn_s_setprio(1);
#pragma unroll
        for (int i = 0; i < 8; i++)
#pragma unroll
            for (int j = 0; j < NF; j++)
                acc[i][j] = __builtin_amdgcn_mfma_f32_16x16x32_bf16(av[i], bv[j], acc[i][j], 0, 0, 0);
        __builtin_amdgcn_s_setprio(0);

        if (kt < NT - 2) waitvm<VW>();   // next tile landed; prefetch stays in flight
        else             waitvm<0>();
        __builtin_amdgcn_s_barrier();

        cur += 1; if (cur == 3) cur = 0;
    }
#undef STAGE8

    // epilogue: C layout col = lane&15, row = 4*(lane>>4)+r
    const int gr_base = m0 + wr * 128 + (lane >> 4) * 4;
    const int gc_base = n0 + wc * (BN / 4) + rl;
#pragma unroll
    for (int i = 0; i < 8; i++) {
#pragma unroll
        for (int j = 0; j < NF; j++) {
            const int col = gc_base + j * 16;
#pragma unroll
            for (int r = 0; r < 4; r++) {
                const int grow = gr_base + i * 16 + r;
                const int bb = grow >> 11;
                const int nn = grow & 2047;
                if (MODE == 0) {
                    const int sel = col >> 10;       // 0 = Q, 1 = K
                    const int cc = col & 1023;
                    const int hh = cc >> 6;
                    const int dd = cc & 63;
                    const float sc = sel ? 1.0f : QSCALE;
                    Cb[(((size_t)((sel << 6) + (bb << 4) + hh) * SEQ + nn) << 6) + dd] =
                        f2bf(acc[i][j][r] * sc);
                } else {
                    const int hh = col >> 6;
                    const float d = dgp[((bb << 4) + hh) * SEQ + nn];
                    out[(size_t)grow * EMB + col] = acc[i][j][r] * d;
                }
            }
        }
    }
}

// ---------------- diag kernel v11: 32x32 MFMA, v6 staging -----------------
// Qh/Kh head-major [64][2048][64] bf16 (Q pre-scaled by QSCALE).
// Block = (bh, 256-q-row tile): 512 threads = 8 waves x 32 q-rows.
// v6 block-cooperative double-buffered staging (XOR-swizzled granules,
// reg-prefetch, 2 barriers/tile). Hot loop: per 32-k-row sub, 4 ds_read_b128
// (compile-time offsets, broadcast-friendly) + 4 chained 32x32x16 MFMAs +
// 16 exp2 + 16 adds = 1024 scores. Diag numerators via 16x16 global pre-pass;
// final write via shfl handoff using the verified 32x32 C/D layout.
__global__ __launch_bounds__(512, 4) void diag_kernel(const short* __restrict__ Qh,
                                                      const short* __restrict__ Kh,
                                                      float* __restrict__ dgp) {
    const int n = blockIdx.x;
    const int bh = (n & 7) | ((n >> 6) << 3);   // 0..63 (XCD-pinned map)
    const int qt = (n >> 3) & 7;                // 8 q-tiles of 256 rows
    __shared__ short Ksd[2 * 8192];             // 2 bufs x 128 rows x 64

    const int t = threadIdx.x;
    const int lane = t & 63;
    const int w = t >> 6;               // 0..7
    const int qbase = qt * 256 + w * 32;

    const short* Kbh = Kh + (size_t)bh * SEQ * DHEAD;
    const short* Qbh = Qh + (size_t)bh * SEQ * DHEAD;

    // ---- diag numerator pre-pass (16x16 MFMA from global; proven path) ----
    const int rl16 = lane & 15;
    const int g16 = lane >> 4;          // 0..3
    const int kq = g16 * 8;
    const int rr = rl16 - g16 * 4;      // valid lane iff 0 <= rr < 4
    float sdiag[2];
#pragma unroll
    for (int i = 0; i < 2; i++) {
        const int row = qbase + i * 16 + rl16;
        const short8 a0d = *(const short8*)(Qbh + row * DHEAD + kq);
        const short8 a1d = *(const short8*)(Qbh + row * DHEAD + kq + 32);
        const short8 b0d = *(const short8*)(Kbh + row * DHEAD + kq);
        const short8 b1d = *(const short8*)(Kbh + row * DHEAD + kq + 32);
        f32x4 cd = {};
        cd = __builtin_amdgcn_mfma_f32_16x16x32_bf16(a0d, b0d, cd, 0, 0, 0);
        cd = __builtin_amdgcn_mfma_f32_16x16x32_bf16(a1d, b1d, cd, 0, 0, 0);
        sdiag[i] = (rr >= 0 && rr < 4) ? cd[rr] : 0.f;
    }

    // ---- Q fragments for 32x32x16: row = lane&31, k = m*16 + (lane>>5)*8 ----
    const int r32 = lane & 31;
    const int h = lane >> 5;            // 0..1
    short8 aq[4];
    {
        const short* qp = Qbh + (qbase + r32) * DHEAD + h * 8;
#pragma unroll
        for (int m = 0; m < 4; m++)
            aq[m] = *(const short8*)(qp + m * 16);
    }

    // ---- staging map (v6): thread t covers rows t>>3 and +64, granule t&7 ----
    const int sr = t >> 3;              // 0..63
    const int c0 = t & 7;
    const int cs = (c0 ^ (sr & 7)) * 8; // XOR-swizzled granule

    // stage tile 0 into buf 0
    *(short8*)&Ksd[sr * 64 + cs]          = *(const short8*)&Kbh[sr * DHEAD + c0 * 8];
    *(short8*)&Ksd[(sr + 64) * 64 + cs]   = *(const short8*)&Kbh[(sr + 64) * DHEAD + c0 * 8];
    __syncthreads();

    // ---- per-lane read voffsets (hoisted; in-loop offsets are immediates) ----
    // logical octet o = 2m + h at row r32 -> physical o ^ (r32&7)
    int voff[4];
#pragma unroll
    for (int m = 0; m < 4; m++)
        voff[m] = r32 * 64 + (((2 * m + h) ^ (r32 & 7)) * 8);

    f32x16 ssum = {};

#define DCOMP(BUFSEL, SUBBASE)                                                     \
    {                                                                              \
        _Pragma("unroll") for (int sub = 0; sub < 4; ++sub) {                      \
            const int base = (BUFSEL)*8192 + sub * 2048;                           \
            const short8 b0 = *(const short8*)&Ksd[base + voff[0]];                \
            const short8 b1 = *(const short8*)&Ksd[base + voff[1]];                \
            const short8 b2 = *(const short8*)&Ksd[base + voff[2]];                \
            const short8 b3 = *(const short8*)&Ksd[base + voff[3]];                \
            f32x16 c = __builtin_amdgcn_mfma_f32_32x32x16_bf16(aq[0], b0, (f32x16){}, 0, 0, 0); \
            c = __builtin_amdgcn_mfma_f32_32x32x16_bf16(aq[1], b1, c, 0, 0, 0);    \
            c = __builtin_amdgcn_mfma_f32_32x32x16_bf16(aq[2], b2, c, 0, 0, 0);    \
            c = __builtin_amdgcn_mfma_f32_32x32x16_bf16(aq[3], b3, c, 0, 0, 0);    \
            _Pragma("unroll") for (int e = 0; e < 16; ++e)                         \
                ssum[e] += __builtin_amdgcn_exp2f(c[e]);                           \
        }                                                                          \
    }

    for (int kt = 0; kt < 16; kt += 2) {
        // tile kt in buf 0; prefetch kt+1 (kt+1 <= 15 always)
        short8 pa0, pa1;
        {
            const short* src = Kbh + (kt + 1) * 8192;
            pa0 = *(const short8*)&src[sr * DHEAD + c0 * 8];
            pa1 = *(const short8*)&src[(sr + 64) * DHEAD + c0 * 8];
        }
        DCOMP(0, kt);
        __syncthreads();
        *(short8*)&Ksd[8192 + sr * 64 + cs]        = pa0;
        *(short8*)&Ksd[8192 + (sr + 64) * 64 + cs] = pa1;
        __syncthreads();

        // tile kt+1 in buf 1; prefetch kt+2 if it exists
        short8 pb0, pb1;
        const bool more = (kt + 2) < 16;
        if (more) {
            const short* src = Kbh + (kt + 2) * 8192;
            pb0 = *(const short8*)&src[sr * DHEAD + c0 * 8];
            pb1 = *(const short8*)&src[(sr + 64) * DHEAD + c0 * 8];
        }
        DCOMP(1, kt + 1);
        if (more) {
            __syncthreads();
            *(short8*)&Ksd[sr * 64 + cs]        = pb0;
            *(short8*)&Ksd[(sr + 64) * 64 + cs] = pb1;
            __syncthreads();
        }
    }
#undef DCOMP

    // ---- reduce over the 32 k-columns (lanes within each 32-half) ----
#pragma unroll
    for (int e = 0; e < 16; ++e) {
        float v = ssum[e];
        v += __shfl_xor(v, 1);
        v += __shfl_xor(v, 2);
        v += __shfl_xor(v, 4);
        v += __shfl_xor(v, 8);
        v += __shfl_xor(v, 16);
        ssum[e] = v;
    }

    // ---- final write: reg r holds row (r&3)+8*(r>>2)+4h; numerator via shfl ----
#pragma unroll
    for (int r = 0; r < 16; ++r) {
        const int srcl = 40 * ((r >> 2) & 1) + 20 * h + (r & 3);
        const float nm = __shfl(sdiag[r >> 3], srcl);
        if (r32 == r) {
            const int row = (r & 3) + 8 * (r >> 2) + 4 * h;
            dgp[bh * SEQ + qbase + row] = __builtin_amdgcn_exp2f(nm) / ssum[r];
        }
    }
}

extern "C" void kernel_launch(void* const* d_in, const int* in_sizes, int n_in,
                              void* d_out, int out_size, void* d_ws, size_t ws_size,
                              hipStream_t stream) {
    const float* x  = (const float*)d_in[0];
    const float* Wq = (const float*)d_in[1];
    const float* Wk = (const float*)d_in[2];
    const float* Wv = (const float*)d_in[3];
    float* out = (float*)d_out;
    char* ws = (char*)d_ws;

    const size_t xb_off  = 0;
    const size_t wq_off  = xb_off + (size_t)MROWS * EMB * 2;
    const size_t wk_off  = wq_off + (size_t)NW * 2;          // contiguous after wq
    const size_t wv_off  = wk_off + (size_t)NW * 2;
    const size_t q_off   = wv_off + (size_t)NW * 2;
    const size_t k_off   = q_off + (size_t)MROWS * EMB * 2;  // contiguous after q
    const size_t dg_off  = k_off + (size_t)MROWS * EMB * 2;

    short* xb  = (short*)(ws + xb_off);
    short* wqb = (short*)(ws + wq_off);
    short* wvb = (short*)(ws + wv_off);
    short* Qh  = (short*)(ws + q_off);
    short* Kh  = (short*)(ws + k_off);
    float* dgp = (float*)(ws + dg_off);

    const int npack = (MROWS * EMB + 3 * NW) / 2048;   // 5632 blocks

    pack_all<<<npack, 256, 0, stream>>>(x, Wq, Wk, Wv,
                                        (unsigned short*)xb, (unsigned short*)wqb,
                                        out + (size_t)MROWS * EMB);

    // fused Q+K projection: B = [Wq | Wk] (contiguous), N = 2048
    gemm8<0><<<dim3(MROWS / 256, 2048 / 256), 512, 0, stream>>>(
        xb, wqb, (unsigned short*)Qh, nullptr, nullptr);

    diag_kernel<<<512, 512, 0, stream>>>(Qh, Kh, dgp);

    gemm8<1><<<dim3(MROWS / 256, EMB / 128), 512, 0, stream>>>(
        xb, wvb, nullptr, out, dgp);
}